// Round 8
// baseline (137.411 us; speedup 1.0000x reference)
//
#include <hip/hip_runtime.h>

// B=256, A=128, D=5, FA=256, FB=64, C=256, F=320.
// deg==5 (~96.2% rows) -> zero row. ~1250 needy rows need feat(320)@W[deg](320x256).
//
// Ledger:
//   R1: touching d_ws => extra 256MiB re-poison fill. Never use workspace.
//   R2: 512 blocks + serial chunks = 69us (concentration serializes).
//   R5: 4096 blocks, float4 W loads, in-kernel zeroing = 42.5us.
//   R6: memset zeros + per-row full-panel matvec = ~40us kernel.
//   R7: in-kernel zeroing + 8-row-batched panel (89MB) = ~39us kernel.
//   => TWO distinct ~40us bottlenecks, never removed together:
//      (a) in-kernel 33.5MB zeroing crawls at ~0.8TB/s (fillBuffer: 6.5TB/s)
//      (b) per-row panel reads = 400MB hot-L2 @ ~10TB/s
//   R6 fixed (a) but kept (b); R7 fixed (b) but kept (a). This round: both.
//
// Structure:
//   op1: hipMemsetAsync(out, 0, 33.5MB)   -- ~5.3us at fill BW (R6-proven)
//   op2: ngh_kernel = R7's verified kernel minus zero-store phase:
//        256 blocks x 512 thr x 128 rows; per-deg LDS compaction; batches of
//        G=8 rows share one 320KB panel pass (8-wave f-split, float4 loads,
//        1 load feeds 32 FMAs); cross-wave LDS reduce; float4 stores for
//        needy rows only (~1.3MB).

#define NB 256
#define NA 128
#define ND 5
#define NFA 256
#define NFB 64
#define NC 256
#define NF (NFA + NFB)      // 320
#define NROWS (NB * NA)     // 32768
#define RPB 128             // rows per block
#define NBLK (NROWS / RPB)  // 256 blocks -> 1/CU
#define NT 512              // threads -> 8 waves
#define G 8                 // rows per panel pass
#define FPW (NF / 8)        // 40 f-rows per wave

__device__ __forceinline__ float4 fma4(float s, float4 wv, float4 a) {
    a.x = fmaf(s, wv.x, a.x);
    a.y = fmaf(s, wv.y, a.y);
    a.z = fmaf(s, wv.z, a.z);
    a.w = fmaf(s, wv.w, a.w);
    return a;
}

__global__ __launch_bounds__(NT) void ngh_kernel(
    const float* __restrict__ atoms,   // B*A*FA
    const float* __restrict__ bonds,   // B*A*D*FB
    const int*   __restrict__ edges,   // B*A*D
    const float* __restrict__ W,       // D*F*C
    const float* __restrict__ bias,    // D*C
    float* __restrict__ out)           // B*A*C (pre-zeroed by memset)
{
    __shared__ int eds[RPB * ND];                 // 2.5 KB
    __shared__ int cnt_s[ND];
    __shared__ int lists[ND][RPB];                // 2.5 KB
    __shared__ int rows_s[G];
    __shared__ alignas(16) float  feat[NF * G];   // [f][r], 10 KB
    __shared__ alignas(16) float4 red[8][G][64];  // 64 KB (per-wave partials)

    const int t  = threadIdx.x;
    const int r0 = blockIdx.x * RPB;
    const int w  = t >> 6;              // wave 0..7
    const int l  = t & 63;              // lane

    if (t < ND) cnt_s[t] = 0;

    // Stage 640 edge ints, coalesced (512 + 128).
    eds[t] = edges[r0 * ND + t];
    if (t < RPB * ND - NT) eds[NT + t] = edges[r0 * ND + NT + t];
    __syncthreads();

    // Degree scan -> per-deg lists (LOCAL row idx).
    if (t < RPB) {
        int dg = 0;
#pragma unroll
        for (int d = 0; d < ND; ++d) dg += (eds[t * ND + d] != -1) ? 1 : 0;
        if (dg < ND) {
            const int p = atomicAdd(&cnt_s[dg], 1);
            lists[dg][p] = t;
        }
    }
    __syncthreads();

    // Needy batches: all loop bounds/branches below are block-uniform
    // (LDS broadcast reads); barriers never sit behind divergent control.
    for (int d = 0; d < ND; ++d) {
        const int n = cnt_s[d];
        for (int j0 = 0; j0 < n; j0 += G) {
            const int nr = min(G, n - j0);
            if (t < G) rows_s[t] = (t < nr) ? lists[d][j0 + t] : -1;
            __syncthreads();

            // Build feat[f][r]: t<256 atom channels, t in [256,320) bonds.
            if (t < NFA) {
#pragma unroll
                for (int r = 0; r < G; ++r) {
                    const int lrow = rows_s[r];
                    float v = 0.f;
                    if (lrow >= 0) {
                        const int row = r0 + lrow;
                        const int rb  = row & ~(NA - 1);   // b*NA
                        v = atoms[(size_t)row * NFA + t];
#pragma unroll
                        for (int dd = 0; dd < ND; ++dd) {
                            const int e = eds[lrow * ND + dd];
                            if (e != -1) v += atoms[(size_t)(rb + e) * NFA + t];
                        }
                    }
                    feat[t * G + r] = v;
                }
            } else if (t < NFA + NFB) {
                const int f = t - NFA;
#pragma unroll
                for (int r = 0; r < G; ++r) {
                    const int lrow = rows_s[r];
                    float v = 0.f;
                    if (lrow >= 0) {
                        const float* br = bonds + (size_t)(r0 + lrow) * (ND * NFB) + f;
#pragma unroll
                        for (int dd = 0; dd < ND; ++dd) v += br[dd * NFB];
                    }
                    feat[(NFA + f) * G + r] = v;
                }
            }
            __syncthreads();

            // Matvec: wave w owns f in [40w, 40w+40); lane owns 4 channels.
            // Per f: ONE float4 W load (1KB/wave, coalesced) feeds 32 FMAs.
            float4 acc[G];
#pragma unroll
            for (int r = 0; r < G; ++r) acc[r] = make_float4(0.f, 0.f, 0.f, 0.f);
            {
                const float4* f4 = reinterpret_cast<const float4*>(feat);
                const float*  Wd = W + (size_t)d * (NF * NC);
                const int fbase = w * FPW;
#pragma unroll 4
                for (int fi = 0; fi < FPW; ++fi) {
                    const int f = fbase + fi;
                    const float4 wv = *reinterpret_cast<const float4*>(
                        &Wd[(size_t)f * NC + l * 4]);
                    const float4 p0 = f4[f * 2];       // feat[f][0..3] bcast
                    const float4 p1 = f4[f * 2 + 1];   // feat[f][4..7] bcast
                    acc[0] = fma4(p0.x, wv, acc[0]);
                    acc[1] = fma4(p0.y, wv, acc[1]);
                    acc[2] = fma4(p0.z, wv, acc[2]);
                    acc[3] = fma4(p0.w, wv, acc[3]);
                    acc[4] = fma4(p1.x, wv, acc[4]);
                    acc[5] = fma4(p1.y, wv, acc[5]);
                    acc[6] = fma4(p1.z, wv, acc[6]);
                    acc[7] = fma4(p1.w, wv, acc[7]);
                }
            }
#pragma unroll
            for (int r = 0; r < G; ++r) red[w][r][l] = acc[r];   // b128, conflict-free
            __syncthreads();

            // Cross-wave reduce + bias + relu + store: 512 threads = 8 rows x 64 lanes.
            {
                const int r    = t >> 6;
                const int li   = t & 63;
                const int lrow = rows_s[r];
                if (lrow >= 0) {
                    float4 s = red[0][r][li];
#pragma unroll
                    for (int wi = 1; wi < 8; ++wi) {
                        const float4 q = red[wi][r][li];
                        s.x += q.x; s.y += q.y; s.z += q.z; s.w += q.w;
                    }
                    const float4 bv = *reinterpret_cast<const float4*>(
                        &bias[d * NC + li * 4]);
                    float4 o;
                    o.x = fmaxf(s.x + bv.x, 0.f);
                    o.y = fmaxf(s.y + bv.y, 0.f);
                    o.z = fmaxf(s.z + bv.z, 0.f);
                    o.w = fmaxf(s.w + bv.w, 0.f);
                    *reinterpret_cast<float4*>(
                        &out[(size_t)(r0 + lrow) * NC + li * 4]) = o;
                }
            }
            __syncthreads();   // rows_s/feat/red reusable for next batch
        }
    }
}

// ---------------------------------------------------------------------------
extern "C" void kernel_launch(void* const* d_in, const int* in_sizes, int n_in,
                              void* d_out, int out_size, void* d_ws, size_t ws_size,
                              hipStream_t stream) {
    const float* atoms = (const float*)d_in[0];
    const float* bonds = (const float*)d_in[1];
    const int*   edges = (const int*)  d_in[2];
    const float* W     = (const float*)d_in[3];
    const float* bias  = (const float*)d_in[4];
    float*       out   = (float*)d_out;

    // Bulk zeros via the runtime fill path (~6.5 TB/s, R6-proven capturable).
    // d_ws deliberately untouched (re-poison tax, R1).
    hipMemsetAsync(out, 0, (size_t)NROWS * NC * sizeof(float), stream);

    // Needy rows only: batched-panel compute (R7-verified math).
    ngh_kernel<<<dim3(NBLK), dim3(NT), 0, stream>>>(
        atoms, bonds, edges, W, bias, out);
}